// Round 1
// baseline (1087.304 us; speedup 1.0000x reference)
//
#include <hip/hip_runtime.h>
#include <math.h>

#define N_NODES_C 16384
#define N_EDGES_C 196608

__device__ __forceinline__ float silu_f(float x) { return x / (1.0f + expf(-x)); }

// ---------------- CSR build ----------------
__global__ void k_count(const int* __restrict__ rcv, int* __restrict__ counts) {
  int e = blockIdx.x * 256 + threadIdx.x;
  atomicAdd(&counts[rcv[e]], 1);
}

__global__ __launch_bounds__(1024) void k_scan(const int* __restrict__ counts,
                                               int* __restrict__ row_start,
                                               int* __restrict__ cursor) {
  __shared__ int sums[1024];
  const int tid = threadIdx.x;
  int loc[16];
  int s = 0;
#pragma unroll
  for (int i = 0; i < 16; ++i) { loc[i] = counts[tid * 16 + i]; s += loc[i]; }
  sums[tid] = s;
  __syncthreads();
  for (int off = 1; off < 1024; off <<= 1) {
    int t = (tid >= off) ? sums[tid - off] : 0;
    __syncthreads();
    sums[tid] += t;
    __syncthreads();
  }
  int excl = sums[tid] - s;
#pragma unroll
  for (int i = 0; i < 16; ++i) {
    row_start[tid * 16 + i] = excl;
    cursor[tid * 16 + i] = excl;
    excl += loc[i];
  }
  if (tid == 1023) row_start[N_NODES_C] = excl;
}

__global__ void k_fill(const int* __restrict__ rcv, int* __restrict__ cursor,
                       int* __restrict__ elist) {
  int e = blockIdx.x * 256 + threadIdx.x;
  int slot = atomicAdd(&cursor[rcv[e]], 1);
  elist[slot] = e;
}

// ---------------- node element id + embedding ----------------
__global__ void k_elem(const float* __restrict__ attrs, int* __restrict__ elem) {
  int n = blockIdx.x * 256 + threadIdx.x;
  const float* a = attrs + n * 8;
  int best = 0;
  float bv = a[0];
#pragma unroll
  for (int z = 1; z < 8; ++z) {
    if (a[z] > bv) { bv = a[z]; best = z; }
  }
  elem[n] = best;
}

__global__ void k_embed(const float* __restrict__ attrs, const float* __restrict__ Wemb,
                        float* __restrict__ scal0, float* __restrict__ nf) {
  int gid = blockIdx.x * 256 + threadIdx.x;  // N*32 threads
  int n = gid >> 5, c = gid & 31;
  float s = 0.f;
#pragma unroll
  for (int z = 0; z < 8; ++z) s = fmaf(attrs[n * 8 + z], Wemb[z * 32 + c], s);
  scal0[gid] = s;
  float* row = nf + (size_t)n * 512 + c * 16;
  *(float4*)&row[0] = make_float4(s, 0.f, 0.f, 0.f);
  *(float4*)&row[4] = make_float4(0.f, 0.f, 0.f, 0.f);
  *(float4*)&row[8] = make_float4(0.f, 0.f, 0.f, 0.f);
  *(float4*)&row[12] = make_float4(0.f, 0.f, 0.f, 0.f);
}

// ---------------- per-edge radial MLP (+SH on layer 0) ----------------
// wave = 64-edge batch: geometry lane-parallel, MLP serial over edges with
// weight COLUMNS held in VGPRs (lane j owns W[:,j]); h broadcast through
// wave-private LDS (uniform-address b128 reads = free broadcast).
__global__ __launch_bounds__(256) void k_radial(
    const float* __restrict__ pos, const float* __restrict__ shifts,
    const int* __restrict__ snd, const int* __restrict__ rcv,
    const float* __restrict__ W1g, const float* __restrict__ W2g,
    const float* __restrict__ W3g, float* __restrict__ h3out,
    float* __restrict__ Yout, const int writeY) {
  __shared__ __align__(16) float efs[4][64][8];
  __shared__ __align__(16) float hbs[4][64];
  const int wid = threadIdx.x >> 6, lane = threadIdx.x & 63;
  float w1c[8], w2c[64], w3c[64];
#pragma unroll
  for (int k = 0; k < 8; ++k) w1c[k] = W1g[k * 64 + lane];
#pragma unroll
  for (int k = 0; k < 64; ++k) w2c[k] = W2g[k * 64 + lane];
#pragma unroll
  for (int k = 0; k < 64; ++k) w3c[k] = W3g[k * 64 + lane];

  const int base = (blockIdx.x * 4 + wid) * 64;
  const int e = base + lane;
  const int sn = snd[e], rc = rcv[e];
  const float vx = pos[rc * 3 + 0] - pos[sn * 3 + 0] + shifts[e * 3 + 0];
  const float vy = pos[rc * 3 + 1] - pos[sn * 3 + 1] + shifts[e * 3 + 1];
  const float vz = pos[rc * 3 + 2] - pos[sn * 3 + 2] + shifts[e * 3 + 2];
  const float len = sqrtf(vx * vx + vy * vy + vz * vz + 1e-18f);
  const float u = len * 0.2f;  // / R_MAX
  float fc = 0.f;
  if (u < 1.0f) {
    const float u2 = u * u, u5 = u2 * u2 * u;
    fc = 1.0f - 21.0f * u5 + 35.0f * u5 * u - 15.0f * u5 * u2;
  }
  const float pref = 0.6324555320336759f * fc / fmaxf(len, 1e-9f);
  float efv[8];
#pragma unroll
  for (int k = 0; k < 8; ++k) {
    const float pin = 3.14159274f * (float)(k + 1);
    efv[k] = pref * sinf(pin * u);
  }
  *(float4*)&efs[wid][lane][0] = make_float4(efv[0], efv[1], efv[2], efv[3]);
  *(float4*)&efs[wid][lane][4] = make_float4(efv[4], efv[5], efv[6], efv[7]);

  if (writeY) {
    const float il = 1.0f / len;
    const float x = vx * il, y = vy * il, z = vz * il;
    const float x2 = x * x, y2 = y * y, z2 = z * z;
    const float s3 = 1.7320508075688772f;
    const float s15 = 3.872983346207417f;
    const float s5h = 1.118033988749895f;
    const float s35_8 = 2.091650066335189f;
    const float s105 = 10.246950765959598f;
    const float s21_8 = 1.6201851746019651f;
    const float s7h = 1.3228756555322954f;
    const float s105h = 5.123475382979799f;
    float* yp = Yout + (size_t)e * 16;
    *(float4*)&yp[0] = make_float4(1.f, s3 * x, s3 * y, s3 * z);
    *(float4*)&yp[4] = make_float4(s15 * x * y, s15 * y * z, s5h * (3.f * z2 - 1.f), s15 * x * z);
    *(float4*)&yp[8] = make_float4(0.5f * s15 * (x2 - y2), s35_8 * y * (3.f * x2 - y2),
                                   s105 * x * y * z, s21_8 * y * (5.f * z2 - 1.f));
    *(float4*)&yp[12] = make_float4(s7h * z * (5.f * z2 - 3.f), s21_8 * x * (5.f * z2 - 1.f),
                                    s105h * z * (x2 - y2), s35_8 * x * (x2 - 3.f * y2));
  }

  for (int t = 0; t < 64; ++t) {
    const float4 ef0 = *(const float4*)&efs[wid][t][0];
    const float4 ef1 = *(const float4*)&efs[wid][t][4];
    float a1 = ef0.x * w1c[0];
    a1 = fmaf(ef0.y, w1c[1], a1);
    a1 = fmaf(ef0.z, w1c[2], a1);
    a1 = fmaf(ef0.w, w1c[3], a1);
    a1 = fmaf(ef1.x, w1c[4], a1);
    a1 = fmaf(ef1.y, w1c[5], a1);
    a1 = fmaf(ef1.z, w1c[6], a1);
    a1 = fmaf(ef1.w, w1c[7], a1);
    hbs[wid][lane] = silu_f(a1);
    float p0 = 0.f, p1 = 0.f, p2 = 0.f, p3 = 0.f;
#pragma unroll
    for (int k4 = 0; k4 < 16; ++k4) {
      const float4 hb = *(const float4*)&hbs[wid][k4 * 4];
      p0 = fmaf(hb.x, w2c[k4 * 4 + 0], p0);
      p1 = fmaf(hb.y, w2c[k4 * 4 + 1], p1);
      p2 = fmaf(hb.z, w2c[k4 * 4 + 2], p2);
      p3 = fmaf(hb.w, w2c[k4 * 4 + 3], p3);
    }
    hbs[wid][lane] = silu_f((p0 + p1) + (p2 + p3));
    p0 = p1 = p2 = p3 = 0.f;
#pragma unroll
    for (int k4 = 0; k4 < 16; ++k4) {
      const float4 hb = *(const float4*)&hbs[wid][k4 * 4];
      p0 = fmaf(hb.x, w3c[k4 * 4 + 0], p0);
      p1 = fmaf(hb.y, w3c[k4 * 4 + 1], p1);
      p2 = fmaf(hb.z, w3c[k4 * 4 + 2], p2);
      p3 = fmaf(hb.w, w3c[k4 * 4 + 3], p3);
    }
    h3out[(size_t)(base + t) * 64 + lane] = silu_f((p0 + p1) + (p2 + p3));
  }
}

// ---------------- node-gathered W4 GEMM + message scale + segment mean ----
// wave = node; acc cm = r*256 + lane*4 + q  (c = r*16 + lane/4, m = (lane&3)*4+q)
__global__ __launch_bounds__(256) void k_gather(
    const float* __restrict__ h3, const float* __restrict__ W4g,
    const float* __restrict__ Y, const float* __restrict__ scal,
    const int* __restrict__ row_start, const int* __restrict__ elist,
    const int* __restrict__ snd, float* __restrict__ agg) {
  __shared__ __align__(16) float w4s[64 * 512];   // 128 KB, [k][cm]
  __shared__ __align__(16) float hbuf[4][4][64];  // per-wave 4-edge h tiles
  for (int i = threadIdx.x; i < 8192; i += 256)
    ((float4*)w4s)[i] = ((const float4*)W4g)[i];
  __syncthreads();
  const int wid = threadIdx.x >> 6, lane = threadIdx.x & 63;
  const int l3 = lane & 3, lc = lane >> 2;
  for (int n = blockIdx.x * 4 + wid; n < N_NODES_C; n += gridDim.x * 4) {
    const int e0 = row_start[n], e1 = row_start[n + 1];
    float acc[2][4] = {{0.f, 0.f, 0.f, 0.f}, {0.f, 0.f, 0.f, 0.f}};
    for (int c0 = e0; c0 < e1; c0 += 4) {
      int eids[4];
#pragma unroll
      for (int j = 0; j < 4; ++j) eids[j] = (c0 + j < e1) ? elist[c0 + j] : -1;
      float4 yv[4];
      float s0[4], s1[4];
#pragma unroll
      for (int j = 0; j < 4; ++j) {
        if (eids[j] >= 0) {
          yv[j] = *(const float4*)&Y[(size_t)eids[j] * 16 + l3 * 4];
          const int sn = snd[eids[j]];
          s0[j] = scal[sn * 32 + lc];
          s1[j] = scal[sn * 32 + 16 + lc];
        } else {
          yv[j] = make_float4(0.f, 0.f, 0.f, 0.f);
          s0[j] = 0.f;
          s1[j] = 0.f;
        }
      }
#pragma unroll
      for (int j = 0; j < 4; ++j)
        hbuf[wid][j][lane] = (eids[j] >= 0) ? h3[(size_t)eids[j] * 64 + lane] : 0.f;
      float tmp[4][2][4] = {};
#pragma unroll
      for (int k4 = 0; k4 < 16; ++k4) {
        float hh[4][4];
#pragma unroll
        for (int j = 0; j < 4; ++j) {
          const float4 h4 = *(const float4*)&hbuf[wid][j][k4 * 4];
          hh[j][0] = h4.x; hh[j][1] = h4.y; hh[j][2] = h4.z; hh[j][3] = h4.w;
        }
#pragma unroll
        for (int kk = 0; kk < 4; ++kk) {
#pragma unroll
          for (int r = 0; r < 2; ++r) {
            const float4 w = *(const float4*)&w4s[(k4 * 4 + kk) * 512 + r * 256 + lane * 4];
#pragma unroll
            for (int j = 0; j < 4; ++j) {
              tmp[j][r][0] = fmaf(hh[j][kk], w.x, tmp[j][r][0]);
              tmp[j][r][1] = fmaf(hh[j][kk], w.y, tmp[j][r][1]);
              tmp[j][r][2] = fmaf(hh[j][kk], w.z, tmp[j][r][2]);
              tmp[j][r][3] = fmaf(hh[j][kk], w.w, tmp[j][r][3]);
            }
          }
        }
      }
#pragma unroll
      for (int j = 0; j < 4; ++j) {
        const float ys[4] = {yv[j].x, yv[j].y, yv[j].z, yv[j].w};
#pragma unroll
        for (int q = 0; q < 4; ++q) {
          acc[0][q] = fmaf(tmp[j][0][q] * ys[q], s0[j], acc[0][q]);
          acc[1][q] = fmaf(tmp[j][1][q] * ys[q], s1[j], acc[1][q]);
        }
      }
    }
    const float inv12 = (1.0f / 12.0f);
    *(float4*)&agg[(size_t)n * 512 + lane * 4] =
        make_float4(acc[0][0] * inv12, acc[0][1] * inv12, acc[0][2] * inv12, acc[0][3] * inv12);
    *(float4*)&agg[(size_t)n * 512 + 256 + lane * 4] =
        make_float4(acc[1][0] * inv12, acc[1][1] * inv12, acc[1][2] * inv12, acc[1][3] * inv12);
  }
}

// ---------------- per-node: Wlin, quadratic, Wprod + skip, desc out -------
__global__ __launch_bounds__(256) void k_node(
    const float* __restrict__ agg, float* __restrict__ nf,
    const float* __restrict__ Wlin, const float* __restrict__ Wprod,
    const float* __restrict__ Wskip, const float* __restrict__ w2v,
    const float* __restrict__ w3v, const int* __restrict__ elem,
    float* __restrict__ scal_out, float* __restrict__ dout, const int layer) {
  __shared__ __align__(16) float aggs[8][512];
  __shared__ __align__(16) float nfs[8][512];
  __shared__ float bs[8][544];  // pitch 17 per channel row
  const int tid = threadIdx.x;
  const int n0 = blockIdx.x * 8;
  for (int i = tid; i < 1024; i += 256) {
    const int nl = i >> 7, q = i & 127;
    ((float4*)aggs)[i] = ((const float4*)agg)[(size_t)(n0 + nl) * 128 + q];
    ((float4*)nfs)[i] = ((const float4*)nf)[(size_t)(n0 + nl) * 128 + q];
  }
  __syncthreads();
  const int nl = tid >> 5, o = tid & 31;
  const int n = n0 + nl;
  constexpr int SLa[4] = {0, 1, 4, 9};
  constexpr int ELa[4] = {1, 4, 9, 16};
  float a[16];
#pragma unroll
  for (int m = 0; m < 16; ++m) a[m] = 0.f;
#pragma unroll
  for (int l = 0; l < 4; ++l) {
    for (int c = 0; c < 32; ++c) {
      const float w = Wlin[(l * 32 + c) * 32 + o];
#pragma unroll
      for (int m = SLa[l]; m < ELa[l]; ++m) a[m] = fmaf(aggs[nl][c * 16 + m], w, a[m]);
    }
  }
  const float inv = a[0];
  float p2 = 0.f;
#pragma unroll
  for (int m = 0; m < 16; ++m) p2 = fmaf(a[m], a[m], p2);
  a[0] = inv + w2v[o] * p2 + w3v[o] * inv * p2;
#pragma unroll
  for (int m = 0; m < 16; ++m) bs[nl][o * 17 + m] = a[m];
  __syncthreads();
  float outv[16];
#pragma unroll
  for (int m = 0; m < 16; ++m) outv[m] = 0.f;
#pragma unroll
  for (int l = 0; l < 4; ++l) {
    for (int c = 0; c < 32; ++c) {
      const float w = Wprod[(l * 32 + c) * 32 + o];
#pragma unroll
      for (int m = SLa[l]; m < ELa[l]; ++m) outv[m] = fmaf(bs[nl][c * 17 + m], w, outv[m]);
    }
  }
  const int z = elem[n];
  const float* wsk = Wskip + z * 1024;
  for (int c = 0; c < 32; ++c) {
    const float w = wsk[c * 32 + o];
#pragma unroll
    for (int m = 0; m < 16; ++m) outv[m] = fmaf(nfs[nl][c * 16 + m], w, outv[m]);
  }
  float* op = nf + (size_t)n * 512 + o * 16;
  *(float4*)&op[0] = make_float4(outv[0], outv[1], outv[2], outv[3]);
  *(float4*)&op[4] = make_float4(outv[4], outv[5], outv[6], outv[7]);
  *(float4*)&op[8] = make_float4(outv[8], outv[9], outv[10], outv[11]);
  *(float4*)&op[12] = make_float4(outv[12], outv[13], outv[14], outv[15]);
  scal_out[n * 32 + o] = outv[0];
  dout[(size_t)n * 64 + layer * 32 + o] = outv[0];
}

extern "C" void kernel_launch(void* const* d_in, const int* in_sizes, int n_in,
                              void* d_out, int out_size, void* d_ws, size_t ws_size,
                              hipStream_t stream) {
  const float* pos = (const float*)d_in[0];
  const float* attrs = (const float*)d_in[1];
  const float* shifts = (const float*)d_in[2];
  const int* eidx = (const int*)d_in[3];
  const float* W_embed = (const float*)d_in[4];
  const float* W1 = (const float*)d_in[5];
  const float* W2 = (const float*)d_in[6];
  const float* W3 = (const float*)d_in[7];
  const float* W4 = (const float*)d_in[8];
  const float* Wlin = (const float*)d_in[9];
  const float* Wskip = (const float*)d_in[10];
  const float* w2v = (const float*)d_in[11];
  const float* w3v = (const float*)d_in[12];
  const float* Wprod = (const float*)d_in[13];
  float* out = (float*)d_out;
  const int* snd = eidx;
  const int* rcv = eidx + N_EDGES_C;

  char* p = (char*)d_ws;
  auto take = [&](size_t bytes) {
    char* q = p;
    p += (bytes + 255) & ~(size_t)255;
    return q;
  };
  int* counts = (int*)take((size_t)N_NODES_C * 4);
  int* row_start = (int*)take((size_t)(N_NODES_C + 1) * 4);
  int* cursor = (int*)take((size_t)N_NODES_C * 4);
  int* elist = (int*)take((size_t)N_EDGES_C * 4);
  int* elem = (int*)take((size_t)N_NODES_C * 4);
  float* Ybuf = (float*)take((size_t)N_EDGES_C * 16 * 4);
  float* h3 = (float*)take((size_t)N_EDGES_C * 64 * 4);
  float* agg = (float*)take((size_t)N_NODES_C * 512 * 4);
  float* nf = (float*)take((size_t)N_NODES_C * 512 * 4);
  float* scal0 = (float*)take((size_t)N_NODES_C * 32 * 4);
  float* scal1 = (float*)take((size_t)N_NODES_C * 32 * 4);
  (void)ws_size; (void)in_sizes; (void)n_in; (void)out_size;

  hipMemsetAsync(counts, 0, (size_t)N_NODES_C * 4, stream);
  k_count<<<N_EDGES_C / 256, 256, 0, stream>>>(rcv, counts);
  k_scan<<<1, 1024, 0, stream>>>(counts, row_start, cursor);
  k_fill<<<N_EDGES_C / 256, 256, 0, stream>>>(rcv, cursor, elist);
  k_elem<<<N_NODES_C / 256, 256, 0, stream>>>(attrs, elem);
  k_embed<<<N_NODES_C * 32 / 256, 256, 0, stream>>>(attrs, W_embed, scal0, nf);

  for (int i = 0; i < 2; ++i) {
    k_radial<<<768, 256, 0, stream>>>(pos, shifts, snd, rcv,
                                      W1 + (size_t)i * 8 * 64, W2 + (size_t)i * 64 * 64,
                                      W3 + (size_t)i * 64 * 64, h3, Ybuf, i == 0 ? 1 : 0);
    k_gather<<<256, 256, 0, stream>>>(h3, W4 + (size_t)i * 64 * 512, Ybuf,
                                      i == 0 ? scal0 : scal1, row_start, elist, snd, agg);
    k_node<<<N_NODES_C / 8, 256, 0, stream>>>(agg, nf, Wlin + (size_t)i * 4096,
                                              Wprod + (size_t)i * 4096, Wskip + (size_t)i * 8192,
                                              w2v + (size_t)i * 32, w3v + (size_t)i * 32, elem,
                                              scal1, out, i);
  }
}